// Round 7
// baseline (269.382 us; speedup 1.0000x reference)
//
#include <hip/hip_runtime.h>

#define BB 512
#define TTOK 196
#define DD 256
#define ROWSTRIDE (TTOK * DD)   // bytes between consecutive b rows (fp8 = 1B/elem)
#define TCHUNK 14
#define NCHUNK 14               // 196 / 14
#define BK 128                  // k bytes (elems) per stage
#define NSTAGE (TCHUNK * 2)     // 2 k-stages per t (D=256)

typedef __attribute__((ext_vector_type(4))) float floatx4;
typedef __attribute__((address_space(3))) char* lds_t;
typedef const __attribute__((address_space(1))) void* gas_t;

// Kernel 1: per-token L2-normalize + cast to OCP fp8 e4m3, [B,T,D] layout.
// LDS-STAGED two-phase (GEMM-staging structure). Six register-level variants
// (R0-R6) all pinned at 1.7-2.0 TB/s: short waves that consume their loads
// immediately cap outstanding misses per CU (~64 lines x 128B / 900cy ~ 9
// B/cy/CU = 2.3 TB/s chip-wide). Fix: per block, stage 32 tokens (32KB) via
// 8 x global_load_lds(16B) per thread - a dependency-free direct-to-LDS
// burst (no VGPR round trip, no consumption stall) - then one vmcnt drain
// at __syncthreads, then compute out of LDS. 32KB -> 5 blocks/CU; resident
// blocks overlap fetch and compute like the GEMM's staging. Compute phase
// = R6's proven mapping: 16-lane group per token, float4 LDS reads at
// u*1024 + it*256 + m*16 (bank = m*4 mod 32, 8 lanes/bank distinct addrs =
// conflict-free b128 baseline), 4-step 8/4/2/1 butterfly, pack, store.
// Arithmetic order bit-identical to R6 (absmax stayed 0).
__global__ __launch_bounds__(256) void k_norm2(const float* __restrict__ text,
                                               const float* __restrict__ visual,
                                               unsigned char* __restrict__ An,
                                               unsigned char* __restrict__ Vn) {
  __shared__ char smem[32768];            // 32 tokens x 256 f32
  const float* in = blockIdx.y ? visual : text;
  unsigned char* out = blockIdx.y ? Vn : An;
  const int tid = threadIdx.x;
  const int wave = tid >> 6;
  const int lane = tid & 63;
  const int g = lane >> 4;                // token within wave-pass (0..3)
  const int m = lane & 15;                // sub-lane within token group
  const int ub0 = blockIdx.x * 32;        // first token of this block

  // Phase 1: stage 32KB, linear, direct-to-LDS (wave-uniform base + lane*16)
  const char* gsrc = (const char*)in + (size_t)ub0 * DD * sizeof(float);
  lds_t lds = (lds_t)smem;
#pragma unroll
  for (int q = 0; q < 8; ++q)
    __builtin_amdgcn_global_load_lds(
        (gas_t)(gsrc + q * 4096 + tid * 16),
        (__attribute__((address_space(3))) void*)(lds + q * 4096 + tid * 16),
        16, 0, 0);
  __syncthreads();                        // drains vmcnt(0): tile resident

  // Phase 2: two passes of 16 tokens (4 waves x 4 token-groups)
#pragma unroll
  for (int p = 0; p < 2; ++p) {
    const int ul = p * 16 + wave * 4 + g; // token within block (0..31)
    const char* tok = smem + ul * 1024;
    float4 v0 = *(const float4*)(tok + 0 * 256 + m * 16);
    float4 v1 = *(const float4*)(tok + 1 * 256 + m * 16);
    float4 v2 = *(const float4*)(tok + 2 * 256 + m * 16);
    float4 v3 = *(const float4*)(tok + 3 * 256 + m * 16);

    float ss = v0.x * v0.x + v0.y * v0.y + v0.z * v0.z + v0.w * v0.w;
    ss += v1.x * v1.x + v1.y * v1.y + v1.z * v1.z + v1.w * v1.w;
    ss += v2.x * v2.x + v2.y * v2.y + v2.z * v2.z + v2.w * v2.w;
    ss += v3.x * v3.x + v3.y * v3.y + v3.z * v3.z + v3.w * v3.w;

    // 4-step butterfly within the 16-lane token group
#pragma unroll
    for (int off = 8; off; off >>= 1) ss += __shfl_xor(ss, off, 64);

    float inv = ss > 1e-24f ? 1.0f / sqrtf(ss) : 0.0f;

    // v_cvt_pk_fp8_f32: byte0=src0, byte1=src1; word_sel=1 fills high word
    int a0 = __builtin_amdgcn_cvt_pk_fp8_f32(v0.x * inv, v0.y * inv, 0, false);
    int p0 = __builtin_amdgcn_cvt_pk_fp8_f32(v0.z * inv, v0.w * inv, a0, true);
    int a1 = __builtin_amdgcn_cvt_pk_fp8_f32(v1.x * inv, v1.y * inv, 0, false);
    int p1 = __builtin_amdgcn_cvt_pk_fp8_f32(v1.z * inv, v1.w * inv, a1, true);
    int a2 = __builtin_amdgcn_cvt_pk_fp8_f32(v2.x * inv, v2.y * inv, 0, false);
    int p2 = __builtin_amdgcn_cvt_pk_fp8_f32(v2.z * inv, v2.w * inv, a2, true);
    int a3 = __builtin_amdgcn_cvt_pk_fp8_f32(v3.x * inv, v3.y * inv, 0, false);
    int p3 = __builtin_amdgcn_cvt_pk_fp8_f32(v3.z * inv, v3.w * inv, a3, true);

    int* op = (int*)(out + (size_t)(ub0 + ul) * DD) + m;
    op[0] = p0;
    op[16] = p1;
    op[32] = p2;
    op[48] = p3;
  }
}

// Kernel 2: fused fp8 GEMM+pool, 64(b)x128(c) block tile, BK=128 (full half-D
// per stage -> 28 stages, half the barriers of the bf16 version).
// Grid (8,4,NCHUNK)=448 blocks, XCD-swizzled (flat&7 -> xcd) so blocks of one
// z-chunk co-locate per XCD and share t-slabs in L2. 4 waves (2x2): wave tile
// 32x64 = 2x4 x mfma_f32_16x16x32_fp8_fp8 per 32-k step. Staging 24KB/stage
// (A 8KB + B 16KB) via global_load_lds w16, double-buffered 48KB -> 3 blk/CU.
// XOR-granule source swizzle (slot p of row r holds granule p^(r&7), granule
// = 16B) keeps LDS stores linear (m104); fragments read as ds_read_b64 at
// slot = ((k0>>4)+(quad>>1))^(row&7), half = quad&1 -> <=2-way aliasing.
__global__ __launch_bounds__(256, 3) void k_gemm_pool(
    const unsigned char* __restrict__ An, const unsigned char* __restrict__ Vn,
    float2* __restrict__ partial) {
  __shared__ char smem[49152];
  const int tid = threadIdx.x;
  const int wave = tid >> 6, lane = tid & 63;
  const int wr = wave >> 1, wc = wave & 1;
  const int lm = lane & 15, quad = lane >> 4, l7 = lane & 7;

  // XCD-aware remap: hw dispatch round-robins flat id over 8 XCDs (flat&7)
  int flat = blockIdx.x + 8 * blockIdx.y + 32 * blockIdx.z;
  int xcd = flat & 7, j = flat >> 3;
  int virt = xcd * 56 + j;          // 56 contiguous work items per XCD
  int vz = virt >> 5;               // 32 blocks per z-chunk
  int rst = virt & 31;
  int vy = rst >> 3, vx = rst & 7;
  const int row_base = vx * 64;     // b tile (A rows)
  const int col_base = vy * 128;    // c tile (B rows)
  const int t0 = vz * TCHUNK;

  // Staging source offsets (bytes). Linear LDS 16B-slot s = q*256+tid ->
  // row r = s>>3 (8 granules/row of 128B), slot p = s&7 holds granule
  // g = p ^ (r&7): source byte = (base+r)*ROWSTRIDE + g*16 (+ t*DD + kb).
  unsigned aoffs[2], boffs[4];
#pragma unroll
  for (int q = 0; q < 2; q++) {
    int s = q * 256 + tid;
    int r = s >> 3;
    int g = (s & 7) ^ (r & 7);
    aoffs[q] = (unsigned)(row_base + r) * ROWSTRIDE + (unsigned)g * 16;
  }
#pragma unroll
  for (int q = 0; q < 4; q++) {
    int s = q * 256 + tid;
    int r = s >> 3;
    int g = (s & 7) ^ (r & 7);
    boffs[q] = (unsigned)(col_base + r) * ROWSTRIDE + (unsigned)g * 16;
  }
  lds_t lds = (lds_t)smem;
  const unsigned ldsoff = (unsigned)tid * 16u;

  floatx4 acc[2][4], sacc[2][4], wacc[2][4];
#pragma unroll
  for (int i = 0; i < 2; i++)
#pragma unroll
    for (int n = 0; n < 4; n++) {
      acc[i][n] = (floatx4){0.f, 0.f, 0.f, 0.f};
      sacc[i][n] = (floatx4){0.f, 0.f, 0.f, 0.f};
      wacc[i][n] = (floatx4){0.f, 0.f, 0.f, 0.f};
    }

  auto issue = [&](int st, int buf) {
    int t = t0 + (st >> 1);
    unsigned kb = (unsigned)(st & 1) * BK;
    const unsigned char* Ab = An + (size_t)t * DD + kb;
    const unsigned char* Bb = Vn + (size_t)t * DD + kb;
    unsigned lb = (unsigned)buf * 24576u + ldsoff;
#pragma unroll
    for (int q = 0; q < 2; q++)
      __builtin_amdgcn_global_load_lds((gas_t)(Ab + aoffs[q]),
                                       (__attribute__((address_space(3))) void*)(lds + lb + (unsigned)q * 4096u),
                                       16, 0, 0);
#pragma unroll
    for (int q = 0; q < 4; q++)
      __builtin_amdgcn_global_load_lds((gas_t)(Bb + boffs[q]),
                                       (__attribute__((address_space(3))) void*)(lds + lb + 8192u + (unsigned)q * 4096u),
                                       16, 0, 0);
  };

  // Fragment row byte-offsets (row stride = BK = 128 B)
  unsigned aRow[2], bRow[4];
#pragma unroll
  for (int i = 0; i < 2; i++) aRow[i] = (unsigned)(wr * 32 + i * 16 + lm) * 128u;
#pragma unroll
  for (int n = 0; n < 4; n++) bRow[n] = (unsigned)(wc * 64 + n * 16 + lm) * 128u;
  const unsigned half8 = (unsigned)(quad & 1) * 8u;

  issue(0, 0);
  for (int st = 0; st < NSTAGE; ++st) {
    int buf = st & 1;
    __syncthreads();               // drains vmcnt -> buf ready; buf^1 free
    if (st + 1 < NSTAGE) issue(st + 1, buf ^ 1);
    const char* A = smem + buf * 24576;
    const char* B = A + 8192;
#pragma unroll
    for (int k0 = 0; k0 < BK; k0 += 32) {
      unsigned slot = (unsigned)(((k0 >> 4) + (quad >> 1)) ^ l7);
      unsigned off = slot * 16u + half8;
      long a[2], b[4];
#pragma unroll
      for (int mi = 0; mi < 2; mi++) a[mi] = *(const long*)(A + aRow[mi] + off);
#pragma unroll
      for (int ni = 0; ni < 4; ni++) b[ni] = *(const long*)(B + bRow[ni] + off);
#pragma unroll
      for (int mi = 0; mi < 2; mi++)
#pragma unroll
        for (int ni = 0; ni < 4; ni++)
          acc[mi][ni] = __builtin_amdgcn_mfma_f32_16x16x32_fp8_fp8(a[mi], b[ni], acc[mi][ni], 0, 0, 0);
    }
    if (st & 1) {   // end of one t (2 stages = full D): fold into pool sums
#pragma unroll
      for (int mi = 0; mi < 2; mi++)
#pragma unroll
        for (int ni = 0; ni < 4; ni++) {
#pragma unroll
          for (int r = 0; r < 4; r++) {
            float c = acc[mi][ni][r];
            float e = __expf(c - 1.0f);
            sacc[mi][ni][r] += e;
            wacc[mi][ni][r] = fmaf(c, e, wacc[mi][ni][r]);
          }
          acc[mi][ni] = (floatx4){0.f, 0.f, 0.f, 0.f};
        }
    }
  }

  // C/D layout (m89-verified, dtype-independent m121-128): col=lane&15,
  // row = quad*4 + r
  size_t cb = (size_t)vz * (BB * BB);
#pragma unroll
  for (int mi = 0; mi < 2; mi++) {
    int bi = row_base + wr * 32 + mi * 16 + quad * 4;
#pragma unroll
    for (int r = 0; r < 4; r++)
#pragma unroll
      for (int ni = 0; ni < 4; ni++) {
        int ci = col_base + wc * 64 + ni * 16 + lm;
        partial[cb + (size_t)(bi + r) * BB + ci] = make_float2(sacc[mi][ni][r], wacc[mi][ni][r]);
      }
  }
}

// Kernel 3: merge chunk partials -> logits = (w/s)/TEMPERATURE
__global__ __launch_bounds__(256) void k_merge(const float2* __restrict__ partial,
                                               float* __restrict__ logits) {
  int idx = blockIdx.x * 256 + threadIdx.x;
  float s = 0.f, w = 0.f;
#pragma unroll
  for (int ch = 0; ch < NCHUNK; ++ch) {
    float2 p = partial[(size_t)ch * (BB * BB) + idx];
    s += p.x;
    w += p.y;
  }
  logits[idx] = (w / s) * (1.0f / 0.07f);
}

// Kernel 4: per-b row-LSE and col-LSE of logits; contrib[b]=2*L[b,b]-lse_r-lse_c
__global__ __launch_bounds__(256) void k_lse(const float* __restrict__ logits,
                                             float* __restrict__ contrib) {
  int b = blockIdx.x;
  int tid = threadIdx.x;
  __shared__ float sm[4];

  float r0 = logits[(size_t)b * BB + tid];
  float r1 = logits[(size_t)b * BB + tid + 256];
  float c0 = logits[(size_t)tid * BB + b];
  float c1 = logits[((size_t)tid + 256) * BB + b];

  float v = fmaxf(r0, r1);
#pragma unroll
  for (int off = 32; off; off >>= 1) v = fmaxf(v, __shfl_xor(v, off, 64));
  if ((tid & 63) == 0) sm[tid >> 6] = v;
  __syncthreads();
  float mr = fmaxf(fmaxf(sm[0], sm[1]), fmaxf(sm[2], sm[3]));
  __syncthreads();
  v = __expf(r0 - mr) + __expf(r1 - mr);
#pragma unroll
  for (int off = 32; off; off >>= 1) v += __shfl_xor(v, off, 64);
  if ((tid & 63) == 0) sm[tid >> 6] = v;
  __syncthreads();
  float sr = sm[0] + sm[1] + sm[2] + sm[3];
  __syncthreads();
  v = fmaxf(c0, c1);
#pragma unroll
  for (int off = 32; off; off >>= 1) v = fmaxf(v, __shfl_xor(v, off, 64));
  if ((tid & 63) == 0) sm[tid >> 6] = v;
  __syncthreads();
  float mc = fmaxf(fmaxf(sm[0], sm[1]), fmaxf(sm[2], sm[3]));
  __syncthreads();
  v = __expf(c0 - mc) + __expf(c1 - mc);
#pragma unroll
  for (int off = 32; off; off >>= 1) v += __shfl_xor(v, off, 64);
  if ((tid & 63) == 0) sm[tid >> 6] = v;
  __syncthreads();
  float sc = sm[0] + sm[1] + sm[2] + sm[3];

  if (tid == 0) {
    float diag = logits[(size_t)b * BB + b];
    contrib[b] = 2.f * diag - (mr + logf(sr)) - (mc + logf(sc));
  }
}

// Kernel 5: loss = -(1/1024) * sum_b contrib[b]
__global__ __launch_bounds__(256) void k_final(const float* __restrict__ contrib,
                                               float* __restrict__ out) {
  int tid = threadIdx.x;
  float v = contrib[tid] + contrib[tid + 256];
#pragma unroll
  for (int off = 32; off; off >>= 1) v += __shfl_xor(v, off, 64);
  __shared__ float sm[4];
  if ((tid & 63) == 0) sm[tid >> 6] = v;
  __syncthreads();
  if (tid == 0) out[0] = -(sm[0] + sm[1] + sm[2] + sm[3]) * (1.0f / 1024.0f);
}

extern "C" void kernel_launch(void* const* d_in, const int* in_sizes, int n_in,
                              void* d_out, int out_size, void* d_ws, size_t ws_size,
                              hipStream_t stream) {
  const float* text = (const float*)d_in[0];
  const float* visual = (const float*)d_in[1];

  char* ws = (char*)d_ws;
  const size_t szN = (size_t)TTOK * BB * DD;                            // 25,690,112 B (fp8)
  const size_t szP = (size_t)NCHUNK * BB * BB * sizeof(float2);         // 29,360,128 B
  unsigned char* An = (unsigned char*)ws;
  unsigned char* Vn = (unsigned char*)(ws + szN);
  float2* partial = (float2*)(ws + 2 * szN);
  float* logits = (float*)(ws + 2 * szN + szP);
  float* contrib = (float*)(ws + 2 * szN + szP + (size_t)BB * BB * sizeof(float));

  k_norm2<<<dim3(BB * TTOK / 32, 2), 256, 0, stream>>>(text, visual, An, Vn);
  k_gemm_pool<<<dim3(8, 4, NCHUNK), 256, 0, stream>>>(An, Vn, partial);
  k_merge<<<BB * BB / 256, 256, 0, stream>>>(partial, logits);
  k_lse<<<BB, 256, 0, stream>>>(logits, contrib);
  k_final<<<1, 256, 0, stream>>>(contrib, (float*)d_out);
}

// Round 8
// 258.059 us; speedup vs baseline: 1.0439x; 1.0439x over previous
//
#include <hip/hip_runtime.h>

#define BB 512
#define TTOK 196
#define DD 256
#define ROWSTRIDE (TTOK * DD)   // bytes between consecutive b rows (fp8 = 1B/elem)
#define TCHUNK 14
#define NCHUNK 14               // 196 / 14
#define BK 128                  // k bytes (elems) per stage
#define NSTAGE (TCHUNK * 2)     // 2 k-stages per t (D=256)

typedef __attribute__((ext_vector_type(4))) float floatx4;
typedef __attribute__((address_space(3))) char* lds_t;
typedef const __attribute__((address_space(1))) void* gas_t;

// Kernel 1: per-token L2-normalize + cast to OCP fp8 e4m3, [B,T,D] layout.
// One wave per token; lane holds 4 consecutive elems -> packs 1 dword of fp8.
// THE R0 ORIGINAL (75.4us measured) — restored after 7 rounds of structural
// experiments (16-lane groups / serial loops / flat-8 / flat-4 / LDS-staged
// burst) all measured 82-92us. Every alternative that raised bytes-per-wave
// lost more to either TA transactions (stride-64B lanes), compiler
// re-serialization (8-token payloads collapsed to 36-VGPR chunked
// schedules), or block-serial drain (LDS staging, occ 34%). This stream's
// ~2TB/s wall is structure-invariant; R0 is its empirical optimum.
__global__ __launch_bounds__(256) void k_norm2(const float* __restrict__ text,
                                               const float* __restrict__ visual,
                                               unsigned char* __restrict__ An,
                                               unsigned char* __restrict__ Vn) {
  const float* in = blockIdx.y ? visual : text;
  unsigned char* out = blockIdx.y ? Vn : An;
  int u = blockIdx.x * 4 + threadIdx.y;   // token id
  int lane = threadIdx.x;                 // 0..63
  float4 v = *((const float4*)(in + (size_t)u * DD) + lane);
  float ss = v.x * v.x + v.y * v.y + v.z * v.z + v.w * v.w;
#pragma unroll
  for (int off = 32; off; off >>= 1) ss += __shfl_xor(ss, off, 64);
  float inv = ss > 1e-24f ? 1.0f / sqrtf(ss) : 0.0f;
  // v_cvt_pk_fp8_f32: byte0=src0, byte1=src1; word_sel=1 fills high word
  int lo = __builtin_amdgcn_cvt_pk_fp8_f32(v.x * inv, v.y * inv, 0, false);
  int packed = __builtin_amdgcn_cvt_pk_fp8_f32(v.z * inv, v.w * inv, lo, true);
  *((int*)(out + (size_t)u * DD) + lane) = packed;
}

// Kernel 2: fused fp8 GEMM+pool, 64(b)x64(c) block tile, BK=128.
// RE-TILED from 64x128 (grid 448 = 1.75 blk/CU, 7 waves/CU, 22% occ - the
// per-stage vmcnt(0)+barrier drain had <2 blocks/CU of cross-block overlap
// to hide under, and 64 CUs idled half the makespan). Now grid (8,8,14) =
// 896 blocks = 3.5 blk/CU, 14 waves/CU; LDS 16KB/stage (A 8KB + B 8KB),
// dbuf 32KB -> 4 blk/CU by LDS, launch_bounds(256,4). Per-XCD z-chunk slab
// (A+B = 3.6MB) now fits the 4MB L2. Partial buffer layout unchanged.
// 4 waves (2x2): wave tile 32x32 = 2x2 x mfma_f32_16x16x32_fp8_fp8 per
// 32-k step. XOR-granule source swizzle preserved verbatim (slot p of row
// r holds granule p^(r&7), granule = 16B); fragments read as ds_read_b64
// at slot = ((k0>>4)+(quad>>1))^(row&7), half = quad&1; row&7 == lm&7
// invariant holds for all wave/frag offsets (multiples of 8).
__global__ __launch_bounds__(256, 4) void k_gemm_pool(
    const unsigned char* __restrict__ An, const unsigned char* __restrict__ Vn,
    float2* __restrict__ partial) {
  __shared__ char smem[32768];
  const int tid = threadIdx.x;
  const int wave = tid >> 6, lane = tid & 63;
  const int wr = wave >> 1, wc = wave & 1;
  const int lm = lane & 15, quad = lane >> 4, l7 = lane & 7;

  // XCD-aware remap: hw dispatch round-robins flat id over 8 XCDs (flat&7)
  int flat = blockIdx.x + 8 * blockIdx.y + 64 * blockIdx.z;
  int xcd = flat & 7, j = flat >> 3;
  int virt = xcd * 112 + j;         // 112 contiguous work items per XCD
  int vz = virt >> 6;               // 64 blocks per z-chunk
  int rst = virt & 63;
  int vy = rst >> 3, vx = rst & 7;  // vx fastest: 8 blocks share a B slab
  const int row_base = vx * 64;     // b tile (A rows)
  const int col_base = vy * 64;     // c tile (B rows)
  const int t0 = vz * TCHUNK;

  // Staging source offsets (bytes). Linear LDS 16B-slot s = q*256+tid ->
  // row r = s>>3 (8 granules/row of 128B), slot p = s&7 holds granule
  // g = p ^ (r&7): source byte = (base+r)*ROWSTRIDE + g*16 (+ t*DD + kb).
  unsigned aoffs[2], boffs[2];
#pragma unroll
  for (int q = 0; q < 2; q++) {
    int s = q * 256 + tid;
    int r = s >> 3;
    int g = (s & 7) ^ (r & 7);
    aoffs[q] = (unsigned)(row_base + r) * ROWSTRIDE + (unsigned)g * 16;
    boffs[q] = (unsigned)(col_base + r) * ROWSTRIDE + (unsigned)g * 16;
  }
  lds_t lds = (lds_t)smem;
  const unsigned ldsoff = (unsigned)tid * 16u;

  floatx4 acc[2][2], sacc[2][2], wacc[2][2];
#pragma unroll
  for (int i = 0; i < 2; i++)
#pragma unroll
    for (int n = 0; n < 2; n++) {
      acc[i][n] = (floatx4){0.f, 0.f, 0.f, 0.f};
      sacc[i][n] = (floatx4){0.f, 0.f, 0.f, 0.f};
      wacc[i][n] = (floatx4){0.f, 0.f, 0.f, 0.f};
    }

  auto issue = [&](int st, int buf) {
    int t = t0 + (st >> 1);
    unsigned kb = (unsigned)(st & 1) * BK;
    const unsigned char* Ab = An + (size_t)t * DD + kb;
    const unsigned char* Bb = Vn + (size_t)t * DD + kb;
    unsigned lb = (unsigned)buf * 16384u + ldsoff;
#pragma unroll
    for (int q = 0; q < 2; q++)
      __builtin_amdgcn_global_load_lds((gas_t)(Ab + aoffs[q]),
                                       (__attribute__((address_space(3))) void*)(lds + lb + (unsigned)q * 4096u),
                                       16, 0, 0);
#pragma unroll
    for (int q = 0; q < 2; q++)
      __builtin_amdgcn_global_load_lds((gas_t)(Bb + boffs[q]),
                                       (__attribute__((address_space(3))) void*)(lds + lb + 8192u + (unsigned)q * 4096u),
                                       16, 0, 0);
  };

  // Fragment row byte-offsets (row stride = BK = 128 B)
  unsigned aRow[2], bRow[2];
#pragma unroll
  for (int i = 0; i < 2; i++) aRow[i] = (unsigned)(wr * 32 + i * 16 + lm) * 128u;
#pragma unroll
  for (int n = 0; n < 2; n++) bRow[n] = (unsigned)(wc * 32 + n * 16 + lm) * 128u;
  const unsigned half8 = (unsigned)(quad & 1) * 8u;

  issue(0, 0);
  for (int st = 0; st < NSTAGE; ++st) {
    int buf = st & 1;
    __syncthreads();               // drains vmcnt -> buf ready; buf^1 free
    if (st + 1 < NSTAGE) issue(st + 1, buf ^ 1);
    const char* A = smem + buf * 16384;
    const char* B = A + 8192;
#pragma unroll
    for (int k0 = 0; k0 < BK; k0 += 32) {
      unsigned slot = (unsigned)(((k0 >> 4) + (quad >> 1)) ^ l7);
      unsigned off = slot * 16u + half8;
      long a[2], b[2];
#pragma unroll
      for (int mi = 0; mi < 2; mi++) a[mi] = *(const long*)(A + aRow[mi] + off);
#pragma unroll
      for (int ni = 0; ni < 2; ni++) b[ni] = *(const long*)(B + bRow[ni] + off);
#pragma unroll
      for (int mi = 0; mi < 2; mi++)
#pragma unroll
        for (int ni = 0; ni < 2; ni++)
          acc[mi][ni] = __builtin_amdgcn_mfma_f32_16x16x32_fp8_fp8(a[mi], b[ni], acc[mi][ni], 0, 0, 0);
    }
    if (st & 1) {   // end of one t (2 stages = full D): fold into pool sums
#pragma unroll
      for (int mi = 0; mi < 2; mi++)
#pragma unroll
        for (int ni = 0; ni < 2; ni++) {
#pragma unroll
          for (int r = 0; r < 4; r++) {
            float c = acc[mi][ni][r];
            float e = __expf(c - 1.0f);
            sacc[mi][ni][r] += e;
            wacc[mi][ni][r] = fmaf(c, e, wacc[mi][ni][r]);
          }
          acc[mi][ni] = (floatx4){0.f, 0.f, 0.f, 0.f};
        }
    }
  }

  // C/D layout (m89-verified, dtype-independent m121-128): col=lane&15,
  // row = quad*4 + r
  size_t cb = (size_t)vz * (BB * BB);
#pragma unroll
  for (int mi = 0; mi < 2; mi++) {
    int bi = row_base + wr * 32 + mi * 16 + quad * 4;
#pragma unroll
    for (int r = 0; r < 4; r++)
#pragma unroll
      for (int ni = 0; ni < 2; ni++) {
        int ci = col_base + wc * 32 + ni * 16 + lm;
        partial[cb + (size_t)(bi + r) * BB + ci] = make_float2(sacc[mi][ni][r], wacc[mi][ni][r]);
      }
  }
}

// Kernel 3: merge chunk partials -> logits = (w/s)/TEMPERATURE
__global__ __launch_bounds__(256) void k_merge(const float2* __restrict__ partial,
                                               float* __restrict__ logits) {
  int idx = blockIdx.x * 256 + threadIdx.x;
  float s = 0.f, w = 0.f;
#pragma unroll
  for (int ch = 0; ch < NCHUNK; ++ch) {
    float2 p = partial[(size_t)ch * (BB * BB) + idx];
    s += p.x;
    w += p.y;
  }
  logits[idx] = (w / s) * (1.0f / 0.07f);
}

// Kernel 4: per-b row-LSE and col-LSE of logits; contrib[b]=2*L[b,b]-lse_r-lse_c
__global__ __launch_bounds__(256) void k_lse(const float* __restrict__ logits,
                                             float* __restrict__ contrib) {
  int b = blockIdx.x;
  int tid = threadIdx.x;
  __shared__ float sm[4];

  float r0 = logits[(size_t)b * BB + tid];
  float r1 = logits[(size_t)b * BB + tid + 256];
  float c0 = logits[(size_t)tid * BB + b];
  float c1 = logits[((size_t)tid + 256) * BB + b];

  float v = fmaxf(r0, r1);
#pragma unroll
  for (int off = 32; off; off >>= 1) v = fmaxf(v, __shfl_xor(v, off, 64));
  if ((tid & 63) == 0) sm[tid >> 6] = v;
  __syncthreads();
  float mr = fmaxf(fmaxf(sm[0], sm[1]), fmaxf(sm[2], sm[3]));
  __syncthreads();
  v = __expf(r0 - mr) + __expf(r1 - mr);
#pragma unroll
  for (int off = 32; off; off >>= 1) v += __shfl_xor(v, off, 64);
  if ((tid & 63) == 0) sm[tid >> 6] = v;
  __syncthreads();
  float sr = sm[0] + sm[1] + sm[2] + sm[3];
  __syncthreads();
  v = fmaxf(c0, c1);
#pragma unroll
  for (int off = 32; off; off >>= 1) v = fmaxf(v, __shfl_xor(v, off, 64));
  if ((tid & 63) == 0) sm[tid >> 6] = v;
  __syncthreads();
  float mc = fmaxf(fmaxf(sm[0], sm[1]), fmaxf(sm[2], sm[3]));
  __syncthreads();
  v = __expf(c0 - mc) + __expf(c1 - mc);
#pragma unroll
  for (int off = 32; off; off >>= 1) v += __shfl_xor(v, off, 64);
  if ((tid & 63) == 0) sm[tid >> 6] = v;
  __syncthreads();
  float sc = sm[0] + sm[1] + sm[2] + sm[3];

  if (tid == 0) {
    float diag = logits[(size_t)b * BB + b];
    contrib[b] = 2.f * diag - (mr + logf(sr)) - (mc + logf(sc));
  }
}

// Kernel 5: loss = -(1/1024) * sum_b contrib[b]
__global__ __launch_bounds__(256) void k_final(const float* __restrict__ contrib,
                                               float* __restrict__ out) {
  int tid = threadIdx.x;
  float v = contrib[tid] + contrib[tid + 256];
#pragma unroll
  for (int off = 32; off; off >>= 1) v += __shfl_xor(v, off, 64);
  __shared__ float sm[4];
  if ((tid & 63) == 0) sm[tid >> 6] = v;
  __syncthreads();
  if (tid == 0) out[0] = -(sm[0] + sm[1] + sm[2] + sm[3]) * (1.0f / 1024.0f);
}

extern "C" void kernel_launch(void* const* d_in, const int* in_sizes, int n_in,
                              void* d_out, int out_size, void* d_ws, size_t ws_size,
                              hipStream_t stream) {
  const float* text = (const float*)d_in[0];
  const float* visual = (const float*)d_in[1];

  char* ws = (char*)d_ws;
  const size_t szN = (size_t)TTOK * BB * DD;                            // 25,690,112 B (fp8)
  const size_t szP = (size_t)NCHUNK * BB * BB * sizeof(float2);         // 29,360,128 B
  unsigned char* An = (unsigned char*)ws;
  unsigned char* Vn = (unsigned char*)(ws + szN);
  float2* partial = (float2*)(ws + 2 * szN);
  float* logits = (float*)(ws + 2 * szN + szP);
  float* contrib = (float*)(ws + 2 * szN + szP + (size_t)BB * BB * sizeof(float));

  dim3 blk1(64, 4);
  k_norm2<<<dim3(BB * TTOK / 4, 2), blk1, 0, stream>>>(text, visual, An, Vn);
  k_gemm_pool<<<dim3(8, 8, NCHUNK), 256, 0, stream>>>(An, Vn, partial);
  k_merge<<<BB * BB / 256, 256, 0, stream>>>(partial, logits);
  k_lse<<<BB, 256, 0, stream>>>(logits, contrib);
  k_final<<<1, 256, 0, stream>>>(contrib, (float*)d_out);
}